// Round 5
// baseline (567.989 us; speedup 1.0000x reference)
//
#include <hip/hip_runtime.h>
#include <hip/hip_bf16.h>
#include <cmath>

#define N_NODES 8192
#define NFEAT 512
#define NHID 512
#define NCLASS 64
#define NLAYERS 8
#define CAP 96

typedef __attribute__((ext_vector_type(8))) short bf16x8;
typedef __attribute__((ext_vector_type(4))) float f32x4;
typedef unsigned short u16;

__device__ inline float bf2f(short u) {
  union { unsigned int i; float f; } x;
  x.i = ((unsigned int)(u16)u) << 16;
  return x.f;
}
__device__ inline short f2bf(float f) {
  union { float f; unsigned int i; } x;
  x.f = f;
  unsigned int r = x.i + 0x7FFFu + ((x.i >> 16) & 1u);
  return (short)(r >> 16);
}

// ---------------- adjacency extraction: one streaming pass over adj ----------
__global__ __launch_bounds__(256)
void extract_kernel(const float* __restrict__ adj, int* __restrict__ idx,
                    int* __restrict__ cnt, int* __restrict__ colcnt)
{
  __shared__ int s_cnt;
  const int i = blockIdx.x;
  if (threadIdx.x == 0) s_cnt = 0;
  __syncthreads();
  const uint4* row = (const uint4*)(adj + (size_t)i * N_NODES);
  for (int c = threadIdx.x; c < N_NODES / 4; c += 256) {
    uint4 v = row[c];
    if ((v.x | v.y | v.z | v.w) == 0u) continue;  // 0.0f bit pattern is 0
    unsigned int vals[4] = {v.x, v.y, v.z, v.w};
    #pragma unroll
    for (int e = 0; e < 4; ++e) {
      if (vals[e] != 0u) {
        int p = atomicAdd(&s_cnt, 1);
        if (p < CAP) idx[(size_t)i * CAP + p] = c * 4 + e;
        atomicAdd(&colcnt[c * 4 + e], 1);
      }
    }
  }
  __syncthreads();
  if (threadIdx.x == 0) cnt[i] = min(s_cnt, CAP);
}

__global__ __launch_bounds__(256)
void dinv_kernel(const int* __restrict__ colcnt, float* __restrict__ dinv)
{
  int j = blockIdx.x * 256 + threadIdx.x;
  if (j < N_NODES) dinv[j] = 1.0f / sqrtf((float)colcnt[j] + 1.0f); // +1 for identity
}

// ---------------- f32 -> bf16 cast (x) ---------------------------------------
__global__ __launch_bounds__(256)
void cvt_bf16_kernel(const float* __restrict__ src, u16* __restrict__ dst, int n4)
{
  int i = blockIdx.x * 256 + threadIdx.x;
  if (i >= n4) return;
  float4 v = ((const float4*)src)[i];
  ushort4 o;
  o.x = (u16)f2bf(v.x); o.y = (u16)f2bf(v.y);
  o.z = (u16)f2bf(v.z); o.w = (u16)f2bf(v.w);
  ((ushort4*)dst)[i] = o;
}

// ---------------- weight transpose + cast -----------------------------------
// z=0:   Wt[0]  = fc1W^T
// z=1..8: Wt[z] = cB[z-1]*convW[z-1]^T + cA[z-1]*I  (GCNII identity fold)
// z=9:   Wt2    = fc2W^T
struct Coefs { float cA[8]; float cB[8]; };

__global__ __launch_bounds__(256)
void transpose_cast_kernel(const float* __restrict__ fc1W, const float* __restrict__ convW,
                           const float* __restrict__ fc2W,
                           u16* __restrict__ Wt, u16* __restrict__ Wt2, Coefs co)
{
  __shared__ float tile[32][33];
  const int m = blockIdx.z;
  const int k0 = blockIdx.x * 32, n0 = blockIdx.y * 32;
  if (m == 9 && n0 >= 64) return;
  const int tx = threadIdx.x & 31, ty = threadIdx.x >> 5; // 32 x 8
  if (m == 9) {
    #pragma unroll
    for (int r = 0; r < 32; r += 8)
      tile[ty + r][tx] = fc2W[(size_t)(k0 + ty + r) * 64 + n0 + tx];
    __syncthreads();
    #pragma unroll
    for (int r = 0; r < 32; r += 8)
      Wt2[(size_t)(n0 + ty + r) * 512 + k0 + tx] = (u16)f2bf(tile[tx][ty + r]);
    return;
  }
  const float* src = (m == 0) ? fc1W : convW + (size_t)(m - 1) * NHID * NHID;
  u16* dst = Wt + (size_t)m * NHID * NHID;
  float cA = 0.f, cB = 1.f;
  if (m >= 1) { cA = co.cA[m - 1]; cB = co.cB[m - 1]; }
  #pragma unroll
  for (int r = 0; r < 32; r += 8)
    tile[ty + r][tx] = src[(size_t)(k0 + ty + r) * NHID + n0 + tx];
  __syncthreads();
  #pragma unroll
  for (int r = 0; r < 32; r += 8) {
    const int krow = k0 + tx, ncol = n0 + ty + r;
    float val = cB * tile[tx][ty + r];
    if (m >= 1 && krow == ncol) val += cA;
    dst[(size_t)ncol * NHID + krow] = (u16)f2bf(val);
  }
}

// ---------------- register-resident GEMM (no LDS, no barriers) ---------------
// Wave owns 64 rows x 16 cols. B-slice (16 cols x K=512) lives in 64 VGPRs,
// loaded once; A-frags stream from global (L2/L3-resident). 1:1 load:MFMA.
// grid (M/256, N/16), block 256: wave w = rows [bx*256+w*64, +64), cols [by*16,+16).
// Same-bx blocks land on one XCD (ids differ by 32 => same %8) -> A is L2-local.
// MODE 0: v=relu(acc+bias); out0=H0, out1=Hs=dinv*v     [fc1]
// MODE 1: v=relu(acc);      out0=Hs=dinv*v              [layers 0..6]
// MODE 2: v=relu(acc);      out0=H (unscaled)           [layer 7]
template<int MODE>
__global__ __launch_bounds__(256, 4)
void rgemm_kernel(const u16* __restrict__ A, const u16* __restrict__ Bt,
                  const float* __restrict__ bias, const float* __restrict__ dinv,
                  u16* __restrict__ out0, u16* __restrict__ out1)
{
  constexpr int K = 512, N = 512;
  const int wave = threadIdx.x >> 6, lane = threadIdx.x & 63;
  const int lrow = lane & 15, lk = lane >> 4;
  const int mw = blockIdx.x * 256 + wave * 64;
  const int n0 = blockIdx.y * 16;
  const int col = n0 + lrow;

  // B-slice into registers: 16 ks-chunks of bf16x8 (64 VGPR)
  bf16x8 breg[16];
  const u16* Brow = Bt + (size_t)col * K + lk * 8;
  #pragma unroll
  for (int ks = 0; ks < 16; ++ks)
    breg[ks] = *(const bf16x8*)(Brow + ks * 32);

  const float bb = (MODE == 0) ? bias[col] : 0.f;

  #pragma unroll
  for (int mt = 0; mt < 4; ++mt) {
    const u16* Arow = A + (size_t)(mw + mt * 16 + lrow) * K + lk * 8;
    f32x4 acc0 = (f32x4){0.f, 0.f, 0.f, 0.f};
    f32x4 acc1 = (f32x4){0.f, 0.f, 0.f, 0.f};
    #pragma unroll
    for (int ks = 0; ks < 16; ks += 2) {
      bf16x8 a0 = *(const bf16x8*)(Arow + ks * 32);
      bf16x8 a1 = *(const bf16x8*)(Arow + ks * 32 + 32);
      acc0 = __builtin_amdgcn_mfma_f32_16x16x32_bf16(a0, breg[ks],     acc0, 0, 0, 0);
      acc1 = __builtin_amdgcn_mfma_f32_16x16x32_bf16(a1, breg[ks + 1], acc1, 0, 0, 0);
    }
    #pragma unroll
    for (int r = 0; r < 4; ++r) {
      const int row = mw + mt * 16 + lk * 4 + r;   // C/D: row=(lane>>4)*4+reg, col=lane&15
      const size_t o = (size_t)row * N + col;
      float v = acc0[r] + acc1[r];
      if (MODE == 0) {
        v = fmaxf(v + bb, 0.f);
        out0[o] = (u16)f2bf(v);                 // H0
        out1[o] = (u16)f2bf(dinv[row] * v);     // Hs
      } else {
        v = fmaxf(v, 0.f);
        out0[o] = (u16)f2bf(MODE == 1 ? dinv[row] * v : v);
      }
    }
  }
}

// ---------------- fc2 + -log_softmax (MFMA, N=64), LDS staging --------------
#define AS1 __attribute__((address_space(1)))
#define AS3 __attribute__((address_space(3)))

__device__ inline void load16(const void* g, void* l) {
  __builtin_amdgcn_global_load_lds((const AS1 void*)g, (AS3 void*)l, 16, 0, 0);
}

__global__ __launch_bounds__(256, 4)
void fc2_kernel(const u16* __restrict__ A, const u16* __restrict__ Bt,
                const float* __restrict__ bias, float* __restrict__ outF)
{
  constexpr int K = 512;
  __shared__ u16 lds[2][2][64 * 64];   // [buf][A/B][tile]  32 KB
  const int tid = threadIdx.x;
  const int wave = tid >> 6, lane = tid & 63;
  const int cpx = gridDim.x >> 3;
  const int logical = (blockIdx.x & 7) * cpx + (blockIdx.x >> 3);
  const int m0 = logical * 64, n0 = 0;
  const int wr = wave >> 1, wc = wave & 1;
  const int lrow = lane & 15, lk = lane >> 4;

  f32x4 acc[2][2];
  #pragma unroll
  for (int a = 0; a < 2; ++a)
    #pragma unroll
    for (int b = 0; b < 2; ++b)
      acc[a][b] = (f32x4){0.f, 0.f, 0.f, 0.f};

  auto stage = [&](int b, int ks) {
    #pragma unroll
    for (int r = 0; r < 2; ++r) {
      const int c = r * 256 + wave * 64 + lane;
      const int row = c >> 3;
      const int sc = (c & 7) ^ (row & 7);
      load16(A  + (size_t)(m0 + row) * K + ks + sc * 8, &lds[b][0][(r * 256 + wave * 64) * 8]);
      load16(Bt + (size_t)(n0 + row) * K + ks + sc * 8, &lds[b][1][(r * 256 + wave * 64) * 8]);
    }
  };

  stage(0, 0);
  __syncthreads();

  for (int t = 0; t < 8; ++t) {
    const int b = t & 1;
    if (t + 1 < 8) stage(b ^ 1, (t + 1) * 64);
    const char* pA = (const char*)lds[b][0];
    const char* pB = (const char*)lds[b][1];
    bf16x8 af[2][2], bfr[2][2];
    #pragma unroll
    for (int mi = 0; mi < 2; ++mi) {
      const int row = wr * 32 + mi * 16 + lrow;
      #pragma unroll
      for (int ks2 = 0; ks2 < 2; ++ks2) {
        const int j = ks2 * 4 + lk;
        af[mi][ks2] = *(const bf16x8*)(pA + row * 128 + ((j ^ (row & 7)) * 16));
      }
    }
    #pragma unroll
    for (int ni = 0; ni < 2; ++ni) {
      const int row = wc * 32 + ni * 16 + lrow;
      #pragma unroll
      for (int ks2 = 0; ks2 < 2; ++ks2) {
        const int j = ks2 * 4 + lk;
        bfr[ni][ks2] = *(const bf16x8*)(pB + row * 128 + ((j ^ (row & 7)) * 16));
      }
    }
    #pragma unroll
    for (int ks2 = 0; ks2 < 2; ++ks2)
      #pragma unroll
      for (int mi = 0; mi < 2; ++mi)
        #pragma unroll
        for (int ni = 0; ni < 2; ++ni)
          acc[mi][ni] = __builtin_amdgcn_mfma_f32_16x16x32_bf16(af[mi][ks2], bfr[ni][ks2], acc[mi][ni], 0, 0, 0);
    __syncthreads();
  }

  // logits (+bias) -> LDS, then per-row softmax (lane = class)
  float* Cf = (float*)&lds[0][0][0];              // 64x65 f32
  #pragma unroll
  for (int mi = 0; mi < 2; ++mi)
    #pragma unroll
    for (int ni = 0; ni < 2; ++ni)
      #pragma unroll
      for (int r = 0; r < 4; ++r) {
        const int row = wr * 32 + mi * 16 + lk * 4 + r;
        const int cc = wc * 32 + ni * 16 + lrow;
        if (cc < NCLASS) Cf[row * 65 + cc] = acc[mi][ni][r] + bias[cc];
      }
  __syncthreads();
  #pragma unroll 4
  for (int r = 0; r < 16; ++r) {
    const int row = wave * 16 + r;
    const float v = Cf[row * 65 + lane];
    float mx = v;
    #pragma unroll
    for (int off = 32; off > 0; off >>= 1) mx = fmaxf(mx, __shfl_xor(mx, off));
    float s = __expf(v - mx);
    #pragma unroll
    for (int off = 32; off > 0; off >>= 1) s += __shfl_xor(s, off);
    outF[(size_t)(m0 + row) * NCLASS + lane] = -(v - mx - logf(s));
  }
}

// ---------------- SpMM: IR = 0.9*(P@H) + 0.1*H0, H pre-scaled ---------------
// Row ownership XCD-aligned to rgemm's A m-chunks: row r on XCD (r/256)%8,
// so IR writes are L2-local for the following GEMM's A reads.
__global__ __launch_bounds__(256)
void spmm_kernel(const u16* __restrict__ Hs, const u16* __restrict__ H0,
                 const float* __restrict__ dinv, const int* __restrict__ idx,
                 const int* __restrict__ cnt, u16* __restrict__ IR)
{
  const int wave = threadIdx.x >> 6, lane = threadIdx.x & 63;
  const int b = blockIdx.x;                       // 2048 blocks
  const int c = (b & 7) + 8 * ((b >> 3) >> 6);    // 256-row chunk, chunk%8 = XCD
  const int j64 = (b >> 3) & 63;                  // block within chunk
  const int i = (c * 64 + j64) * 4 + wave;
  const int c0 = lane * 8;
  const int n = cnt[i];
  int jreg = 0;
  if (lane < n) jreg = idx[(size_t)i * CAP + lane] & (N_NODES - 1);

  float acc[8];
  #pragma unroll
  for (int e = 0; e < 8; ++e) acc[e] = 0.f;

  const int nn = min(n, 64);
  int t = 0;
  for (; t + 8 <= nn; t += 8) {          // 8 gathers in flight
    bf16x8 v[8];
    #pragma unroll
    for (int u = 0; u < 8; ++u) {
      const int j = __shfl(jreg, t + u);
      v[u] = *(const bf16x8*)&Hs[(size_t)j * NHID + c0];
    }
    #pragma unroll
    for (int u = 0; u < 8; ++u)
      #pragma unroll
      for (int e = 0; e < 8; ++e)
        acc[e] += bf2f(v[u][e]);
  }
  for (; t < nn; ++t) {
    const int j = __shfl(jreg, t);
    bf16x8 v = *(const bf16x8*)&Hs[(size_t)j * NHID + c0];
    #pragma unroll
    for (int e = 0; e < 8; ++e) acc[e] += bf2f(v[e]);
  }
  for (; t < n; ++t) {                   // n > 64: essentially never
    const int j = idx[(size_t)i * CAP + t] & (N_NODES - 1);
    bf16x8 v = *(const bf16x8*)&Hs[(size_t)j * NHID + c0];
    #pragma unroll
    for (int e = 0; e < 8; ++e) acc[e] += bf2f(v[e]);
  }

  const float di = dinv[i];
  bf16x8 self = *(const bf16x8*)&Hs[(size_t)i * NHID + c0];
  bf16x8 h0   = *(const bf16x8*)&H0[(size_t)i * NHID + c0];
  bf16x8 ov;
  #pragma unroll
  for (int e = 0; e < 8; ++e) {
    float v = 0.9f * di * (acc[e] + bf2f(self[e])) + 0.1f * bf2f(h0[e]);
    ov[e] = f2bf(v);
  }
  *(bf16x8*)&IR[(size_t)i * NHID + c0] = ov;
}

// ---------------- launch -----------------------------------------------------
extern "C" void kernel_launch(void* const* d_in, const int* in_sizes, int n_in,
                              void* d_out, int out_size, void* d_ws, size_t ws_size,
                              hipStream_t stream)
{
  const float* x     = (const float*)d_in[0];
  const float* adj   = (const float*)d_in[1];
  const float* fc1W  = (const float*)d_in[2];
  const float* fc1b  = (const float*)d_in[3];
  const float* convW = (const float*)d_in[4];
  const float* fc2W  = (const float*)d_in[5];
  const float* fc2b  = (const float*)d_in[6];
  float* out = (float*)d_out;

  char* ws = (char*)d_ws;
  size_t off = 0;
  auto alloc = [&](size_t bytes) -> void* {
    void* p = ws + off;
    off = (off + bytes + 255) & ~(size_t)255;
    return p;
  };
  u16*   xb   = (u16*)alloc((size_t)N_NODES * NFEAT * 2);
  u16*   Wt   = (u16*)alloc((size_t)9 * NHID * NHID * 2);
  u16*   Wt2  = (u16*)alloc((size_t)NCLASS * NHID * 2);
  u16*   H0   = (u16*)alloc((size_t)N_NODES * NHID * 2);
  u16*   HsA  = (u16*)alloc((size_t)N_NODES * NHID * 2);
  u16*   HsB  = (u16*)alloc((size_t)N_NODES * NHID * 2);
  u16*   IR   = (u16*)alloc((size_t)N_NODES * NHID * 2);
  int*   idx  = (int*)alloc((size_t)N_NODES * CAP * 4);
  int*   cnt  = (int*)alloc((size_t)N_NODES * 4);
  int*   colc = (int*)alloc((size_t)N_NODES * 4);
  float* dinv = (float*)alloc((size_t)N_NODES * 4);

  Coefs co;
  for (int i = 0; i < NLAYERS; ++i) {
    const double beta = log(0.5 / (double)(i + 1) + 1.0);
    co.cA[i] = (float)(1.0 - beta);
    co.cB[i] = (float)beta;
  }

  hipMemsetAsync(colc, 0, N_NODES * 4, stream);
  extract_kernel<<<N_NODES, 256, 0, stream>>>(adj, idx, cnt, colc);
  dinv_kernel<<<N_NODES / 256, 256, 0, stream>>>(colc, dinv);
  cvt_bf16_kernel<<<(N_NODES * NFEAT / 4) / 256, 256, 0, stream>>>(x, xb, N_NODES * NFEAT / 4);
  transpose_cast_kernel<<<dim3(16, 16, 10), 256, 0, stream>>>(fc1W, convW, fc2W, Wt, Wt2, co);

  // fc1: H0 = relu(x@W+b), Hs = dinv*H0
  rgemm_kernel<0><<<dim3(32, 32), 256, 0, stream>>>(xb, Wt, fc1b, dinv, H0, HsA);

  const u16* Hin = HsA;
  for (int i = 0; i < NLAYERS; ++i) {
    spmm_kernel<<<N_NODES / 4, 256, 0, stream>>>(Hin, H0, dinv, idx, cnt, IR);
    u16* Hout = (Hin == HsA) ? HsB : HsA;
    if (i < NLAYERS - 1)
      rgemm_kernel<1><<<dim3(32, 32), 256, 0, stream>>>(
          IR, Wt + (size_t)(i + 1) * NHID * NHID, nullptr, dinv, Hout, nullptr);
    else
      rgemm_kernel<2><<<dim3(32, 32), 256, 0, stream>>>(
          IR, Wt + (size_t)(i + 1) * NHID * NHID, nullptr, dinv, Hout, nullptr);
    Hin = Hout;
  }

  // fc2 + -log_softmax (MFMA, N=64)
  fc2_kernel<<<128, 256, 0, stream>>>((const u16*)Hin, Wt2, fc2b, out);
}

// Round 6
// 319.537 us; speedup vs baseline: 1.7775x; 1.7775x over previous
//
#include <hip/hip_runtime.h>
#include <hip/hip_bf16.h>
#include <cmath>

#define N_NODES 8192
#define NFEAT 512
#define NHID 512
#define NCLASS 64
#define NLAYERS 8
#define CAP 96

typedef __attribute__((ext_vector_type(8))) short bf16x8;
typedef __attribute__((ext_vector_type(4))) float f32x4;
typedef unsigned short u16;

__device__ inline float bf2f(short u) {
  union { unsigned int i; float f; } x;
  x.i = ((unsigned int)(u16)u) << 16;
  return x.f;
}
__device__ inline short f2bf(float f) {
  union { float f; unsigned int i; } x;
  x.f = f;
  unsigned int r = x.i + 0x7FFFu + ((x.i >> 16) & 1u);
  return (short)(r >> 16);
}

// ---------------- adjacency extraction: one streaming pass over adj ----------
__global__ __launch_bounds__(256)
void extract_kernel(const float* __restrict__ adj, int* __restrict__ idx,
                    int* __restrict__ cnt, int* __restrict__ colcnt)
{
  __shared__ int s_cnt;
  const int i = blockIdx.x;
  if (threadIdx.x == 0) s_cnt = 0;
  __syncthreads();
  const uint4* row = (const uint4*)(adj + (size_t)i * N_NODES);
  for (int c = threadIdx.x; c < N_NODES / 4; c += 256) {
    uint4 v = row[c];
    if ((v.x | v.y | v.z | v.w) == 0u) continue;  // 0.0f bit pattern is 0
    unsigned int vals[4] = {v.x, v.y, v.z, v.w};
    #pragma unroll
    for (int e = 0; e < 4; ++e) {
      if (vals[e] != 0u) {
        int p = atomicAdd(&s_cnt, 1);
        if (p < CAP) idx[(size_t)i * CAP + p] = c * 4 + e;
        atomicAdd(&colcnt[c * 4 + e], 1);
      }
    }
  }
  __syncthreads();
  if (threadIdx.x == 0) cnt[i] = min(s_cnt, CAP);
}

__global__ __launch_bounds__(256)
void dinv_kernel(const int* __restrict__ colcnt, float* __restrict__ dinv)
{
  int j = blockIdx.x * 256 + threadIdx.x;
  if (j < N_NODES) dinv[j] = 1.0f / sqrtf((float)colcnt[j] + 1.0f); // +1 for identity
}

// ---------------- f32 -> bf16 cast (x) ---------------------------------------
__global__ __launch_bounds__(256)
void cvt_bf16_kernel(const float* __restrict__ src, u16* __restrict__ dst, int n4)
{
  int i = blockIdx.x * 256 + threadIdx.x;
  if (i >= n4) return;
  float4 v = ((const float4*)src)[i];
  ushort4 o;
  o.x = (u16)f2bf(v.x); o.y = (u16)f2bf(v.y);
  o.z = (u16)f2bf(v.z); o.w = (u16)f2bf(v.w);
  ((ushort4*)dst)[i] = o;
}

// ---------------- weight transpose + cast -----------------------------------
// z=0:   Wt[0]  = fc1W^T
// z=1..8: Wt[z] = cB[z-1]*convW[z-1]^T + cA[z-1]*I  (GCNII identity fold)
// z=9:   Wt2    = fc2W^T
struct Coefs { float cA[8]; float cB[8]; };

__global__ __launch_bounds__(256)
void transpose_cast_kernel(const float* __restrict__ fc1W, const float* __restrict__ convW,
                           const float* __restrict__ fc2W,
                           u16* __restrict__ Wt, u16* __restrict__ Wt2, Coefs co)
{
  __shared__ float tile[32][33];
  const int m = blockIdx.z;
  const int k0 = blockIdx.x * 32, n0 = blockIdx.y * 32;
  if (m == 9 && n0 >= 64) return;
  const int tx = threadIdx.x & 31, ty = threadIdx.x >> 5; // 32 x 8
  if (m == 9) {
    #pragma unroll
    for (int r = 0; r < 32; r += 8)
      tile[ty + r][tx] = fc2W[(size_t)(k0 + ty + r) * 64 + n0 + tx];
    __syncthreads();
    #pragma unroll
    for (int r = 0; r < 32; r += 8)
      Wt2[(size_t)(n0 + ty + r) * 512 + k0 + tx] = (u16)f2bf(tile[tx][ty + r]);
    return;
  }
  const float* src = (m == 0) ? fc1W : convW + (size_t)(m - 1) * NHID * NHID;
  u16* dst = Wt + (size_t)m * NHID * NHID;
  float cA = 0.f, cB = 1.f;
  if (m >= 1) { cA = co.cA[m - 1]; cB = co.cB[m - 1]; }
  #pragma unroll
  for (int r = 0; r < 32; r += 8)
    tile[ty + r][tx] = src[(size_t)(k0 + ty + r) * NHID + n0 + tx];
  __syncthreads();
  #pragma unroll
  for (int r = 0; r < 32; r += 8) {
    const int krow = k0 + tx, ncol = n0 + ty + r;
    float val = cB * tile[tx][ty + r];
    if (m >= 1 && krow == ncol) val += cA;
    dst[(size_t)ncol * NHID + krow] = (u16)f2bf(val);
  }
}

// ---------------- MFMA GEMM, 128x64 tile, BK=64, 4x2 frags/wave -------------
#define AS1 __attribute__((address_space(1)))
#define AS3 __attribute__((address_space(3)))

__device__ inline void load16(const void* g, void* l) {
  __builtin_amdgcn_global_load_lds((const AS1 void*)g, (AS3 void*)l, 16, 0, 0);
}

// Grid 512 linear: mblk = bid&63 (A-panel), nblk = bid>>6. All 8 nblks of one
// mblk share bid%8 = mblk%8 -> same XCD -> A re-reads are L2-local.
// Per wave: 64x32 output (4 m-frags x 2 n-frags) -> A-frag reused x2, B x4:
// 12 ds_read_b128 : 16 MFMA per BK=32 half-step — LDS/MFMA balanced.
// MODE 0: v=relu(acc+bias); out0=H0, out1=Hs=dinv*v     [fc1]
// MODE 1: v=relu(acc);      out0=Hs=dinv*v              [layers 0..6]
// MODE 2: v=relu(acc);      out0=H (unscaled)           [layer 7]
template<int MODE>
__global__ __launch_bounds__(256, 2)
void gemm_kernel(const u16* __restrict__ A, const u16* __restrict__ Bt,
                 const float* __restrict__ bias, const float* __restrict__ dinv,
                 u16* __restrict__ out0, u16* __restrict__ out1)
{
  constexpr int K = 512, N = 512;
  constexpr int BM = 128, BN = 64, BK = 64;
  __shared__ u16 ldsA[2][BM * BK];   // 16 KB x2
  __shared__ u16 ldsB[2][BN * BK];   //  8 KB x2   => 48 KB total
  const int tid = threadIdx.x;
  const int wave = tid >> 6, lane = tid & 63;
  const int mblk = blockIdx.x & 63, nblk = blockIdx.x >> 6;
  const int m0 = mblk * BM, n0 = nblk * BN;
  const int wr = wave >> 1, wc = wave & 1;
  const int lrow = lane & 15, lk = lane >> 4;

  f32x4 acc[4][2];
  #pragma unroll
  for (int a = 0; a < 4; ++a)
    #pragma unroll
    for (int b = 0; b < 2; ++b)
      acc[a][b] = (f32x4){0.f, 0.f, 0.f, 0.f};

  // rows of 64 k-elements = 128 B = 8 chunks of 16 B; XOR swizzle j^(row&7)
  // applied on the GLOBAL source chunk (LDS dest linear — rule 21).
  auto stage = [&](int b, int ks) {
    #pragma unroll
    for (int r = 0; r < 4; ++r) {            // A: 1024 chunks
      const int c = r * 256 + wave * 64 + lane;
      const int row = c >> 3, sc = (c & 7) ^ (row & 7);
      load16(A + (size_t)(m0 + row) * K + ks + sc * 8,
             &ldsA[b][(r * 256 + wave * 64) * 8]);
    }
    #pragma unroll
    for (int r = 0; r < 2; ++r) {            // B: 512 chunks
      const int c = r * 256 + wave * 64 + lane;
      const int row = c >> 3, sc = (c & 7) ^ (row & 7);
      load16(Bt + (size_t)(n0 + row) * K + ks + sc * 8,
             &ldsB[b][(r * 256 + wave * 64) * 8]);
    }
  };

  stage(0, 0);
  __syncthreads();

  for (int t = 0; t < K / BK; ++t) {
    const int b = t & 1;
    if (t + 1 < K / BK) stage(b ^ 1, (t + 1) * BK);   // prefetch under compute
    const char* pA = (const char*)ldsA[b];
    const char* pB = (const char*)ldsB[b];
    #pragma unroll
    for (int ks2 = 0; ks2 < 2; ++ks2) {
      const int j = ks2 * 4 + lk;                     // logical 16B chunk
      bf16x8 af[4], bfr[2];
      #pragma unroll
      for (int mi = 0; mi < 4; ++mi) {
        const int row = wr * 64 + mi * 16 + lrow;
        af[mi] = *(const bf16x8*)(pA + row * 128 + ((j ^ (row & 7)) * 16));
      }
      #pragma unroll
      for (int ni = 0; ni < 2; ++ni) {
        const int row = wc * 32 + ni * 16 + lrow;
        bfr[ni] = *(const bf16x8*)(pB + row * 128 + ((j ^ (row & 7)) * 16));
      }
      #pragma unroll
      for (int mi = 0; mi < 4; ++mi)
        #pragma unroll
        for (int ni = 0; ni < 2; ++ni)
          acc[mi][ni] = __builtin_amdgcn_mfma_f32_16x16x32_bf16(af[mi], bfr[ni], acc[mi][ni], 0, 0, 0);
    }
    __syncthreads();
  }

  #pragma unroll
  for (int mi = 0; mi < 4; ++mi) {
    #pragma unroll
    for (int ni = 0; ni < 2; ++ni) {
      #pragma unroll
      for (int r = 0; r < 4; ++r) {
        const int row = m0 + wr * 64 + mi * 16 + lk * 4 + r;
        const int col = n0 + wc * 32 + ni * 16 + lrow;
        const size_t o = (size_t)row * N + col;
        float v = acc[mi][ni][r];
        if (MODE == 0) {
          v = fmaxf(v + bias[col], 0.f);
          out0[o] = (u16)f2bf(v);                 // H0
          out1[o] = (u16)f2bf(dinv[row] * v);     // Hs
        } else {
          v = fmaxf(v, 0.f);
          out0[o] = (u16)f2bf(MODE == 1 ? dinv[row] * v : v);
        }
      }
    }
  }
}

// ---------------- fc2 + -log_softmax (MFMA, N=64), LDS staging --------------
__global__ __launch_bounds__(256, 4)
void fc2_kernel(const u16* __restrict__ A, const u16* __restrict__ Bt,
                const float* __restrict__ bias, float* __restrict__ outF)
{
  constexpr int K = 512;
  __shared__ u16 lds[2][2][64 * 64];   // [buf][A/B][tile]  32 KB
  const int tid = threadIdx.x;
  const int wave = tid >> 6, lane = tid & 63;
  const int cpx = gridDim.x >> 3;
  const int logical = (blockIdx.x & 7) * cpx + (blockIdx.x >> 3);
  const int m0 = logical * 64, n0 = 0;
  const int wr = wave >> 1, wc = wave & 1;
  const int lrow = lane & 15, lk = lane >> 4;

  f32x4 acc[2][2];
  #pragma unroll
  for (int a = 0; a < 2; ++a)
    #pragma unroll
    for (int b = 0; b < 2; ++b)
      acc[a][b] = (f32x4){0.f, 0.f, 0.f, 0.f};

  auto stage = [&](int b, int ks) {
    #pragma unroll
    for (int r = 0; r < 2; ++r) {
      const int c = r * 256 + wave * 64 + lane;
      const int row = c >> 3;
      const int sc = (c & 7) ^ (row & 7);
      load16(A  + (size_t)(m0 + row) * K + ks + sc * 8, &lds[b][0][(r * 256 + wave * 64) * 8]);
      load16(Bt + (size_t)(n0 + row) * K + ks + sc * 8, &lds[b][1][(r * 256 + wave * 64) * 8]);
    }
  };

  stage(0, 0);
  __syncthreads();

  for (int t = 0; t < 8; ++t) {
    const int b = t & 1;
    if (t + 1 < 8) stage(b ^ 1, (t + 1) * 64);
    const char* pA = (const char*)lds[b][0];
    const char* pB = (const char*)lds[b][1];
    bf16x8 af[2][2], bfr[2][2];
    #pragma unroll
    for (int mi = 0; mi < 2; ++mi) {
      const int row = wr * 32 + mi * 16 + lrow;
      #pragma unroll
      for (int ks2 = 0; ks2 < 2; ++ks2) {
        const int j = ks2 * 4 + lk;
        af[mi][ks2] = *(const bf16x8*)(pA + row * 128 + ((j ^ (row & 7)) * 16));
      }
    }
    #pragma unroll
    for (int ni = 0; ni < 2; ++ni) {
      const int row = wc * 32 + ni * 16 + lrow;
      #pragma unroll
      for (int ks2 = 0; ks2 < 2; ++ks2) {
        const int j = ks2 * 4 + lk;
        bfr[ni][ks2] = *(const bf16x8*)(pB + row * 128 + ((j ^ (row & 7)) * 16));
      }
    }
    #pragma unroll
    for (int ks2 = 0; ks2 < 2; ++ks2)
      #pragma unroll
      for (int mi = 0; mi < 2; ++mi)
        #pragma unroll
        for (int ni = 0; ni < 2; ++ni)
          acc[mi][ni] = __builtin_amdgcn_mfma_f32_16x16x32_bf16(af[mi][ks2], bfr[ni][ks2], acc[mi][ni], 0, 0, 0);
    __syncthreads();
  }

  // logits (+bias) -> LDS, then per-row softmax (lane = class)
  float* Cf = (float*)&lds[0][0][0];              // 64x65 f32
  #pragma unroll
  for (int mi = 0; mi < 2; ++mi)
    #pragma unroll
    for (int ni = 0; ni < 2; ++ni)
      #pragma unroll
      for (int r = 0; r < 4; ++r) {
        const int row = wr * 32 + mi * 16 + lk * 4 + r;
        const int cc = wc * 32 + ni * 16 + lrow;
        if (cc < NCLASS) Cf[row * 65 + cc] = acc[mi][ni][r] + bias[cc];
      }
  __syncthreads();
  #pragma unroll 4
  for (int r = 0; r < 16; ++r) {
    const int row = wave * 16 + r;
    const float v = Cf[row * 65 + lane];
    float mx = v;
    #pragma unroll
    for (int off = 32; off > 0; off >>= 1) mx = fmaxf(mx, __shfl_xor(mx, off));
    float s = __expf(v - mx);
    #pragma unroll
    for (int off = 32; off > 0; off >>= 1) s += __shfl_xor(s, off);
    outF[(size_t)(m0 + row) * NCLASS + lane] = -(v - mx - logf(s));
  }
}

// ---------------- SpMM: IR = 0.9*(P@H) + 0.1*H0, H pre-scaled ---------------
__global__ __launch_bounds__(256)
void spmm_kernel(const u16* __restrict__ Hs, const u16* __restrict__ H0,
                 const float* __restrict__ dinv, const int* __restrict__ idx,
                 const int* __restrict__ cnt, u16* __restrict__ IR)
{
  const int wave = threadIdx.x >> 6, lane = threadIdx.x & 63;
  const int i = blockIdx.x * 4 + wave;
  const int c0 = lane * 8;
  const int n = cnt[i];
  int jreg = 0;
  if (lane < n) jreg = idx[(size_t)i * CAP + lane] & (N_NODES - 1);

  float acc[8];
  #pragma unroll
  for (int e = 0; e < 8; ++e) acc[e] = 0.f;

  const int nn = min(n, 64);
  int t = 0;
  for (; t + 8 <= nn; t += 8) {          // 8 gathers in flight
    bf16x8 v[8];
    #pragma unroll
    for (int u = 0; u < 8; ++u) {
      const int j = __shfl(jreg, t + u);
      v[u] = *(const bf16x8*)&Hs[(size_t)j * NHID + c0];
    }
    #pragma unroll
    for (int u = 0; u < 8; ++u)
      #pragma unroll
      for (int e = 0; e < 8; ++e)
        acc[e] += bf2f(v[u][e]);
  }
  for (; t < nn; ++t) {
    const int j = __shfl(jreg, t);
    bf16x8 v = *(const bf16x8*)&Hs[(size_t)j * NHID + c0];
    #pragma unroll
    for (int e = 0; e < 8; ++e) acc[e] += bf2f(v[e]);
  }
  for (; t < n; ++t) {                   // n > 64: essentially never
    const int j = idx[(size_t)i * CAP + t] & (N_NODES - 1);
    bf16x8 v = *(const bf16x8*)&Hs[(size_t)j * NHID + c0];
    #pragma unroll
    for (int e = 0; e < 8; ++e) acc[e] += bf2f(v[e]);
  }

  const float di = dinv[i];
  bf16x8 self = *(const bf16x8*)&Hs[(size_t)i * NHID + c0];
  bf16x8 h0   = *(const bf16x8*)&H0[(size_t)i * NHID + c0];
  bf16x8 ov;
  #pragma unroll
  for (int e = 0; e < 8; ++e) {
    float v = 0.9f * di * (acc[e] + bf2f(self[e])) + 0.1f * bf2f(h0[e]);
    ov[e] = f2bf(v);
  }
  *(bf16x8*)&IR[(size_t)i * NHID + c0] = ov;
}

// ---------------- launch -----------------------------------------------------
extern "C" void kernel_launch(void* const* d_in, const int* in_sizes, int n_in,
                              void* d_out, int out_size, void* d_ws, size_t ws_size,
                              hipStream_t stream)
{
  const float* x     = (const float*)d_in[0];
  const float* adj   = (const float*)d_in[1];
  const float* fc1W  = (const float*)d_in[2];
  const float* fc1b  = (const float*)d_in[3];
  const float* convW = (const float*)d_in[4];
  const float* fc2W  = (const float*)d_in[5];
  const float* fc2b  = (const float*)d_in[6];
  float* out = (float*)d_out;

  char* ws = (char*)d_ws;
  size_t off = 0;
  auto alloc = [&](size_t bytes) -> void* {
    void* p = ws + off;
    off = (off + bytes + 255) & ~(size_t)255;
    return p;
  };
  u16*   xb   = (u16*)alloc((size_t)N_NODES * NFEAT * 2);
  u16*   Wt   = (u16*)alloc((size_t)9 * NHID * NHID * 2);
  u16*   Wt2  = (u16*)alloc((size_t)NCLASS * NHID * 2);
  u16*   H0   = (u16*)alloc((size_t)N_NODES * NHID * 2);
  u16*   HsA  = (u16*)alloc((size_t)N_NODES * NHID * 2);
  u16*   HsB  = (u16*)alloc((size_t)N_NODES * NHID * 2);
  u16*   IR   = (u16*)alloc((size_t)N_NODES * NHID * 2);
  int*   idx  = (int*)alloc((size_t)N_NODES * CAP * 4);
  int*   cnt  = (int*)alloc((size_t)N_NODES * 4);
  int*   colc = (int*)alloc((size_t)N_NODES * 4);
  float* dinv = (float*)alloc((size_t)N_NODES * 4);

  Coefs co;
  for (int i = 0; i < NLAYERS; ++i) {
    const double beta = log(0.5 / (double)(i + 1) + 1.0);
    co.cA[i] = (float)(1.0 - beta);
    co.cB[i] = (float)beta;
  }

  hipMemsetAsync(colc, 0, N_NODES * 4, stream);
  extract_kernel<<<N_NODES, 256, 0, stream>>>(adj, idx, cnt, colc);
  dinv_kernel<<<N_NODES / 256, 256, 0, stream>>>(colc, dinv);
  cvt_bf16_kernel<<<(N_NODES * NFEAT / 4) / 256, 256, 0, stream>>>(x, xb, N_NODES * NFEAT / 4);
  transpose_cast_kernel<<<dim3(16, 16, 10), 256, 0, stream>>>(fc1W, convW, fc2W, Wt, Wt2, co);

  // fc1: H0 = relu(x@W+b), Hs = dinv*H0
  gemm_kernel<0><<<512, 256, 0, stream>>>(xb, Wt, fc1b, dinv, H0, HsA);

  const u16* Hin = HsA;
  for (int i = 0; i < NLAYERS; ++i) {
    spmm_kernel<<<N_NODES / 4, 256, 0, stream>>>(Hin, H0, dinv, idx, cnt, IR);
    u16* Hout = (Hin == HsA) ? HsB : HsA;
    if (i < NLAYERS - 1)
      gemm_kernel<1><<<512, 256, 0, stream>>>(
          IR, Wt + (size_t)(i + 1) * NHID * NHID, nullptr, dinv, Hout, nullptr);
    else
      gemm_kernel<2><<<512, 256, 0, stream>>>(
          IR, Wt + (size_t)(i + 1) * NHID * NHID, nullptr, dinv, Hout, nullptr);
    Hin = Hout;
  }

  // fc2 + -log_softmax (MFMA, N=64)
  fc2_kernel<<<128, 256, 0, stream>>>((const u16*)Hin, Wt2, fc2b, out);
}